// Round 1
// baseline (1049.941 us; speedup 1.0000x reference)
//
#include <hip/hip_runtime.h>
#include <math.h>

#define BB 4
#define SS 2048
#define NH 8
#define HD 64
#define HID 512
#define EPSV 1e-5f

#define NROWS (BB * SS)                    // 8192 (b,s) rows
#define QKV_ELEMS (BB * NH * SS * HD)      // 4,194,304
#define TOTROWS (BB * NH * SS)             // 65536 (b,h,s) rows

// ---------------------------------------------------------------------------
// GEMM: C = A(M x K) @ W(N x K)^T + bias.  M=8192, N=K=512.
// 64x64 tile, 256 threads, 4x4 micro-tile, k-chunk 16 (vectorized float4).
// SPLIT: write C in split-head layout [b, h, s, d] instead of [m, n].
// ---------------------------------------------------------------------------
template <bool SPLIT>
__global__ __launch_bounds__(256) void gemm_xwt(const float* __restrict__ A,
                                                const float* __restrict__ W,
                                                const float* __restrict__ bias,
                                                float* __restrict__ C) {
  __shared__ float As[64][68];
  __shared__ float Ws[64][68];
  const int m0 = blockIdx.y * 64;
  const int n0 = blockIdx.x * 64;
  const int tid = threadIdx.x;
  const int ty = tid >> 4;        // 0..15
  const int tx = tid & 15;        // 0..15
  const int lrow = tid >> 2;      // 0..63
  const int lko = (tid & 3) * 4;  // 0,4,8,12

  float acc[4][4];
#pragma unroll
  for (int r = 0; r < 4; ++r)
#pragma unroll
    for (int c = 0; c < 4; ++c) acc[r][c] = 0.f;

  for (int k0 = 0; k0 < HID; k0 += 16) {
    float4 av = *(const float4*)&A[(size_t)(m0 + lrow) * HID + k0 + lko];
    float4 wv = *(const float4*)&W[(size_t)(n0 + lrow) * HID + k0 + lko];
    __syncthreads();  // protect previous iter reads before overwrite
    *(float4*)&As[lrow][lko] = av;
    *(float4*)&Ws[lrow][lko] = wv;
    __syncthreads();
#pragma unroll
    for (int kk = 0; kk < 16; kk += 4) {
      float4 a[4], w[4];
#pragma unroll
      for (int r = 0; r < 4; ++r) a[r] = *(const float4*)&As[r * 16 + ty][kk];
#pragma unroll
      for (int c = 0; c < 4; ++c) w[c] = *(const float4*)&Ws[c * 16 + tx][kk];
#pragma unroll
      for (int r = 0; r < 4; ++r)
#pragma unroll
        for (int c = 0; c < 4; ++c) {
          acc[r][c] += a[r].x * w[c].x;
          acc[r][c] += a[r].y * w[c].y;
          acc[r][c] += a[r].z * w[c].z;
          acc[r][c] += a[r].w * w[c].w;
        }
    }
  }

#pragma unroll
  for (int r = 0; r < 4; ++r) {
    const int m = m0 + r * 16 + ty;
#pragma unroll
    for (int c = 0; c < 4; ++c) {
      const int n = n0 + c * 16 + tx;
      float v = acc[r][c] + bias[n];
      if (SPLIT) {
        const int b = m >> 11;  // m / SS
        const int s = m & (SS - 1);
        const int h = n >> 6;  // n / HD
        const int d = n & 63;
        C[(((size_t)(b * NH + h)) * SS + s) * HD + d] = v;
      } else {
        C[(size_t)m * HID + n] = v;
      }
    }
  }
}

// ---------------------------------------------------------------------------
// Scores pass: for each (b,h, 64-row i-tile), loop over all j:
//   dist(i,j) = sum_d |Q[i,d]-K[j,d]| ; s = -dist*temp[h] (mask -> -1e9)
// Write raw scores into the attn output region (scratch), and keep online
// per-row (max, sumexp) stats -> stats[].
// ---------------------------------------------------------------------------
__global__ __launch_bounds__(256) void scores_kernel(
    const float* __restrict__ Q, const float* __restrict__ K,
    const int* __restrict__ mask, const float* __restrict__ temp,
    float* __restrict__ attn, float* __restrict__ stats) {
  __shared__ float Qs[64][68];
  __shared__ float Ks[64][68];
  __shared__ int Ms[64];

  const int bh = blockIdx.y;  // b*NH + h
  const int b = bh >> 3;
  const int h = bh & 7;
  const int i0 = blockIdx.x * 64;
  const int tid = threadIdx.x;
  const int ty = tid >> 4;
  const int tx = tid & 15;
  const float tmp = temp[h];

  const float* Qb = Q + (size_t)bh * SS * HD;
  const float* Kb = K + (size_t)bh * SS * HD;
  float* attn_b = attn + (size_t)bh * SS * SS;

// load Q tile (stays resident for whole kernel)
#pragma unroll
  for (int t = 0; t < 4; ++t) {
    int f = t * 256 + tid;  // float4 index, 1024 total
    int row = f >> 4;
    int col = (f & 15) * 4;
    *(float4*)&Qs[row][col] = *(const float4*)&Qb[(size_t)(i0 + row) * HD + col];
  }

  float m[4], sg[4];
#pragma unroll
  for (int r = 0; r < 4; ++r) {
    m[r] = -INFINITY;
    sg[r] = 0.f;
  }

  for (int j0 = 0; j0 < SS; j0 += 64) {
    __syncthreads();  // protect Ks reads from previous iteration
#pragma unroll
    for (int t = 0; t < 4; ++t) {
      int f = t * 256 + tid;
      int row = f >> 4;
      int col = (f & 15) * 4;
      *(float4*)&Ks[row][col] = *(const float4*)&Kb[(size_t)(j0 + row) * HD + col];
    }
    if (tid < 64) Ms[tid] = mask[b * SS + j0 + tid];
    __syncthreads();

    float dist[4][4];
#pragma unroll
    for (int r = 0; r < 4; ++r)
#pragma unroll
      for (int c = 0; c < 4; ++c) dist[r][c] = 0.f;

#pragma unroll
    for (int d4 = 0; d4 < HD; d4 += 4) {
      float4 q[4], kv[4];
#pragma unroll
      for (int r = 0; r < 4; ++r) q[r] = *(const float4*)&Qs[r * 16 + ty][d4];
#pragma unroll
      for (int c = 0; c < 4; ++c) kv[c] = *(const float4*)&Ks[c * 16 + tx][d4];
#pragma unroll
      for (int r = 0; r < 4; ++r)
#pragma unroll
        for (int c = 0; c < 4; ++c) {
          dist[r][c] += fabsf(q[r].x - kv[c].x);
          dist[r][c] += fabsf(q[r].y - kv[c].y);
          dist[r][c] += fabsf(q[r].z - kv[c].z);
          dist[r][c] += fabsf(q[r].w - kv[c].w);
        }
    }

// scores + online softmax stats + store raw scores
#pragma unroll
    for (int r = 0; r < 4; ++r) {
      const int i = i0 + r * 16 + ty;
      float s[4];
      float mloc = m[r];
#pragma unroll
      for (int c = 0; c < 4; ++c) {
        const int jl = c * 16 + tx;
        float sc = -dist[r][c] * tmp;
        if (Ms[jl] == 0) sc = -1e9f;
        s[c] = sc;
        attn_b[(size_t)i * SS + j0 + jl] = sc;
        mloc = fmaxf(mloc, sc);
      }
      float add = 0.f;
#pragma unroll
      for (int c = 0; c < 4; ++c) add += __expf(s[c] - mloc);
      sg[r] = sg[r] * __expf(m[r] - mloc) + add;
      m[r] = mloc;
    }
  }

// reduce (m, sg) across the 16 tx lanes holding the same row
#pragma unroll
  for (int r = 0; r < 4; ++r) {
    float mm = m[r], ss = sg[r];
#pragma unroll
    for (int off = 1; off < 16; off <<= 1) {
      float m2 = __shfl_xor(mm, off);
      float s2 = __shfl_xor(ss, off);
      float mn = fmaxf(mm, m2);
      ss = ss * __expf(mm - mn) + s2 * __expf(m2 - mn);
      mm = mn;
    }
    if (tx == 0) {
      const int row = bh * SS + i0 + r * 16 + ty;
      stats[2 * row] = mm;
      stats[2 * row + 1] = ss;
    }
  }
}

// ---------------------------------------------------------------------------
// Normalize + PV: read raw scores, write attn = exp(s-m)/sigma in place,
// accumulate out = attn @ V, write to attn_out in [b, s, h*64+d] layout.
// ---------------------------------------------------------------------------
__global__ __launch_bounds__(256) void attn_pv_kernel(
    const float* __restrict__ V, const float* __restrict__ stats,
    float* __restrict__ attn, float* __restrict__ attn_out) {
  __shared__ float Vs[64][68];
  __shared__ float Ps[64][68];

  const int bh = blockIdx.y;
  const int b = bh >> 3;
  const int h = bh & 7;
  const int i0 = blockIdx.x * 64;
  const int tid = threadIdx.x;
  const int ty = tid >> 4;
  const int tx = tid & 15;

  const float* Vb = V + (size_t)bh * SS * HD;
  float* attn_b = attn + (size_t)bh * SS * SS;

  float m[4], inv[4];
#pragma unroll
  for (int r = 0; r < 4; ++r) {
    const int row = bh * SS + i0 + r * 16 + ty;
    m[r] = stats[2 * row];
    inv[r] = 1.0f / stats[2 * row + 1];
  }

  float acc[4][4];
#pragma unroll
  for (int r = 0; r < 4; ++r)
#pragma unroll
    for (int c = 0; c < 4; ++c) acc[r][c] = 0.f;

  for (int j0 = 0; j0 < SS; j0 += 64) {
    __syncthreads();  // protect Vs/Ps from previous iteration
#pragma unroll
    for (int t = 0; t < 4; ++t) {
      int f = t * 256 + tid;
      int row = f >> 4;
      int col = (f & 15) * 4;
      *(float4*)&Vs[row][col] = *(const float4*)&Vb[(size_t)(j0 + row) * HD + col];
    }
// read scores, normalize, write attn in place, stage P tile
#pragma unroll
    for (int r = 0; r < 4; ++r) {
      const int i = i0 + r * 16 + ty;
#pragma unroll
      for (int c = 0; c < 4; ++c) {
        const int jl = c * 16 + tx;
        float s = attn_b[(size_t)i * SS + j0 + jl];
        float p = __expf(s - m[r]) * inv[r];
        attn_b[(size_t)i * SS + j0 + jl] = p;
        Ps[r * 16 + ty][jl] = p;
      }
    }
    __syncthreads();
// PV accumulate: acc[r][c] = sum_j P[i(r)][j] * V[j][d(c)]
#pragma unroll 8
    for (int j = 0; j < 64; ++j) {
      float pr[4], vv[4];
#pragma unroll
      for (int r = 0; r < 4; ++r) pr[r] = Ps[r * 16 + ty][j];
#pragma unroll
      for (int c = 0; c < 4; ++c) vv[c] = Vs[j][c * 16 + tx];
#pragma unroll
      for (int r = 0; r < 4; ++r)
#pragma unroll
        for (int c = 0; c < 4; ++c) acc[r][c] += pr[r] * vv[c];
    }
  }

#pragma unroll
  for (int r = 0; r < 4; ++r) {
    const int s = i0 + r * 16 + ty;
#pragma unroll
    for (int c = 0; c < 4; ++c) {
      const int d = c * 16 + tx;
      attn_out[((size_t)(b * SS + s)) * HID + h * HD + d] = acc[r][c];
    }
  }
}

// ---------------------------------------------------------------------------
// Residual + LayerNorm: out = LN(proj + query) * gamma + beta
// One block (256 threads) per row of 512.
// ---------------------------------------------------------------------------
__global__ __launch_bounds__(256) void ln_kernel(const float* __restrict__ proj,
                                                 const float* __restrict__ query,
                                                 const float* __restrict__ gamma,
                                                 const float* __restrict__ beta,
                                                 float* __restrict__ out) {
  const int row = blockIdx.x;
  const int tid = threadIdx.x;

  float x[2];
  float sum = 0.f, sumsq = 0.f;
#pragma unroll
  for (int t = 0; t < 2; ++t) {
    const int c = tid + t * 256;
    float v = proj[(size_t)row * HID + c] + query[(size_t)row * HID + c];
    x[t] = v;
    sum += v;
    sumsq += v * v;
  }
#pragma unroll
  for (int off = 1; off < 64; off <<= 1) {
    sum += __shfl_xor(sum, off);
    sumsq += __shfl_xor(sumsq, off);
  }
  __shared__ float s1[4], s2[4];
  if ((tid & 63) == 0) {
    s1[tid >> 6] = sum;
    s2[tid >> 6] = sumsq;
  }
  __syncthreads();
  sum = s1[0] + s1[1] + s1[2] + s1[3];
  sumsq = s2[0] + s2[1] + s2[2] + s2[3];
  const float mu = sum * (1.f / HID);
  const float var = sumsq * (1.f / HID) - mu * mu;
  const float rstd = rsqrtf(var + EPSV);
#pragma unroll
  for (int t = 0; t < 2; ++t) {
    const int c = tid + t * 256;
    out[(size_t)row * HID + c] = (x[t] - mu) * rstd * gamma[c] + beta[c];
  }
}

// ---------------------------------------------------------------------------
extern "C" void kernel_launch(void* const* d_in, const int* in_sizes, int n_in,
                              void* d_out, int out_size, void* d_ws, size_t ws_size,
                              hipStream_t stream) {
  const float* query = (const float*)d_in[0];
  const float* key = (const float*)d_in[1];
  const float* value = (const float*)d_in[2];
  const int* mask = (const int*)d_in[3];
  const float* Wq = (const float*)d_in[4];
  const float* bq = (const float*)d_in[5];
  const float* Wk = (const float*)d_in[6];
  const float* bk = (const float*)d_in[7];
  const float* Wv = (const float*)d_in[8];
  const float* bv = (const float*)d_in[9];
  const float* Wo = (const float*)d_in[10];
  const float* bo = (const float*)d_in[11];
  const float* temp = (const float*)d_in[12];
  const float* gamma = (const float*)d_in[13];
  const float* beta = (const float*)d_in[14];

  float* out_final = (float*)d_out;                      // (B,S,HID)
  float* attn = (float*)d_out + (size_t)BB * SS * HID;   // (B,H,S,S)

  float* Qb = (float*)d_ws;          // [B,H,S,D]
  float* Kb = Qb + QKV_ELEMS;        // [B,H,S,D]
  float* Vb = Kb + QKV_ELEMS;        // [B,H,S,D]
  float* stats = Vb + QKV_ELEMS;     // 2 * TOTROWS
  float* attn_out = Qb;              // reuse Q after scores pass: [B,S,HID]
  float* proj = Kb;                  // reuse K after scores pass: [B,S,HID]

  const dim3 blk(256);
  const dim3 ggrid(HID / 64, NROWS / 64);  // 8 x 128

  gemm_xwt<true><<<ggrid, blk, 0, stream>>>(query, Wq, bq, Qb);
  gemm_xwt<true><<<ggrid, blk, 0, stream>>>(key, Wk, bk, Kb);
  gemm_xwt<true><<<ggrid, blk, 0, stream>>>(value, Wv, bv, Vb);

  const dim3 sgrid(SS / 64, BB * NH);  // 32 x 32
  scores_kernel<<<sgrid, blk, 0, stream>>>(Qb, Kb, mask, temp, attn, stats);
  attn_pv_kernel<<<sgrid, blk, 0, stream>>>(Vb, stats, attn, attn_out);

  gemm_xwt<false><<<ggrid, blk, 0, stream>>>(attn_out, Wo, bo, proj);
  ln_kernel<<<NROWS, blk, 0, stream>>>(proj, query, gamma, beta, out_final);
}